// Round 14
// baseline (396.591 us; speedup 1.0000x reference)
//
#include <hip/hip_runtime.h>

#define N_NODES 50000
#define N_EDGES 800000
#define DIN     128
#define H       96
#define K_EXP   8
#define L_LAYERS 4
#define C_OUT   40

typedef _Float16 f16;
typedef f16 f16x2 __attribute__((ext_vector_type(2)));
typedef f16 f16x4 __attribute__((ext_vector_type(4)));
typedef f16 f16x8 __attribute__((ext_vector_type(8)));
typedef float f32x4 __attribute__((ext_vector_type(4)));

// ---------------- CSR build + weight conversion (merged) ----------------

#define CONV_TOT (L_LAYERS * K_EXP * H * H)   // 294912
#define FC0_TOT  (DIN * H)                    // 12288
#define FC1_TOT  (48 * H)                     // 4608
#define CNT_BLOCKS ((N_EDGES + 255) / 256)            // 3125
#define CVT_BLOCKS ((CONV_TOT + FC0_TOT + FC1_TOT + 255) / 256)  // 1218

__global__ __launch_bounds__(256) void count_convert(const int* __restrict__ row,
                                                     int* __restrict__ deg,
                                                     int* __restrict__ p,
                                                     const float* __restrict__ conv_w,
                                                     const float* __restrict__ fc0_w,
                                                     const float* __restrict__ fc1_w,
                                                     f16* __restrict__ wfrag,
                                                     f16* __restrict__ fc0t,
                                                     f16* __restrict__ fc1t) {
    int tid = threadIdx.x;
    if ((int)blockIdx.x < CNT_BLOCKS) {
        int i = blockIdx.x * 256 + tid;
        if (i < N_EDGES) p[i] = atomicAdd(&deg[row[i]], 1);
    } else {
        int i = ((int)blockIdx.x - CNT_BLOCKS) * 256 + tid;
        if (i < CONV_TOT) {
            int o = i % H;
            int t = i / H;
            int d = t % H;
            int lk = t / H;
            int ct = o >> 4, lc = o & 15;
            int ks = d >> 5, quad = (d >> 3) & 3, j = d & 7;
            wfrag[(size_t)lk * 9216 + ct * 1536 + ks * 512 + (quad * 16 + lc) * 8 + j] =
                (f16)conv_w[i];
        } else if (i < CONV_TOT + FC0_TOT) {
            int j = i - CONV_TOT;      // j = d*96+o
            int o = j % H, d = j / H;
            fc0t[o * DIN + d] = (f16)fc0_w[j];
        } else if (i < CONV_TOT + FC0_TOT + FC1_TOT) {
            int j = i - CONV_TOT - FC0_TOT;  // target [o][d]
            int o = j / H, d = j % H;
            fc1t[j] = (o < C_OUT) ? (f16)fc1_w[d * C_OUT + o] : (f16)0.f;
        }
    }
}

__global__ __launch_bounds__(1024) void scanA(const int* __restrict__ deg,
                                              int* __restrict__ rowptr,
                                              int* __restrict__ partial, int n) {
    __shared__ int wsum[16];
    int tid  = threadIdx.x;
    int lane = tid & 63, wid = tid >> 6;
    int idx = blockIdx.x * 1024 + tid;
    int v = (idx < n) ? deg[idx] : 0;
    int s = v;
    #pragma unroll
    for (int off = 1; off < 64; off <<= 1) {
        int t = __shfl_up(s, off, 64);
        if (lane >= off) s += t;
    }
    if (lane == 63) wsum[wid] = s;
    __syncthreads();
    if (wid == 0 && lane < 16) {
        int w = wsum[lane];
        #pragma unroll
        for (int off = 1; off < 16; off <<= 1) {
            int t = __shfl_up(w, off, 16);
            if (lane >= off) w += t;
        }
        wsum[lane] = w;
    }
    __syncthreads();
    int waveoff = (wid == 0) ? 0 : wsum[wid - 1];
    if (idx < n) rowptr[idx + 1] = waveoff + s;
    if (tid == 1023) partial[blockIdx.x] = waveoff + s;
}

__global__ __launch_bounds__(1024) void scanC(int* __restrict__ rowptr,
                                              const int* __restrict__ partial,
                                              int nb, int n) {
    __shared__ int boff_s;
    int tid = threadIdx.x;
    if (tid < 64) {
        int v = 0;
        for (int j = tid; j < (int)blockIdx.x; j += 64) v += partial[j];
        #pragma unroll
        for (int off = 32; off >= 1; off >>= 1) v += __shfl_xor(v, off, 64);
        if (tid == 0) boff_s = v;
    }
    __syncthreads();
    int boff = boff_s;
    int idx = blockIdx.x * 1024 + tid;
    if (idx == 0) rowptr[0] = 0;
    if (idx < n) rowptr[idx + 1] += boff;
}

// ---------------- scatter (single pass) + fc0 MFMA, fused into one launch ----------------

#define SCT_BLOCKS 1024
#define FPAD 136

__global__ __launch_bounds__(256) void scatter_fc0(const int* __restrict__ row,
                                                   const int* __restrict__ col,
                                                   const int* __restrict__ p,
                                                   const int* __restrict__ rowptr,
                                                   int* __restrict__ csr,
                                                   const float* __restrict__ x,
                                                   const f16* __restrict__ fc0t,
                                                   const float* __restrict__ b,
                                                   f16* __restrict__ h16, int n) {
    __shared__ f16 As[64 * FPAD];
    __shared__ f16 Ws[96 * FPAD];
    int tid = threadIdx.x;
    if ((int)blockIdx.x < SCT_BLOCKS) {
        int stride = SCT_BLOCKS * 256;
        for (int i = blockIdx.x * 256 + tid; i < N_EDGES; i += stride)
            csr[rowptr[row[i]] + p[i]] = col[i];
        return;
    }
    int l = tid & 63, w = tid >> 6;
    int quad = l >> 4, lc = l & 15;
    int row0 = ((int)blockIdx.x - SCT_BLOCKS) * 64;

    for (int t = tid; t < 2048; t += 256) {
        int m = t >> 5, c4 = (t & 31) * 4;
        int gr = row0 + m;
        float4 v = {0.f, 0.f, 0.f, 0.f};
        if (gr < n) v = *(const float4*)(x + (size_t)gr * DIN + c4);
        f16x4 h4 = {(f16)v.x, (f16)v.y, (f16)v.z, (f16)v.w};
        *(f16x4*)&As[m * FPAD + c4] = h4;
    }
    for (int t = tid; t < 1536; t += 256) {
        int o = t >> 4, c8 = (t & 15) * 8;
        *(f16x8*)&Ws[o * FPAD + c8] = *(const f16x8*)(fc0t + o * DIN + c8);
    }
    __syncthreads();

    f16x8 afr[4];
    #pragma unroll
    for (int ks = 0; ks < 4; ks++)
        afr[ks] = *(const f16x8*)&As[(16 * w + lc) * FPAD + ks * 32 + quad * 8];

    f32x4 acc[6] = {};
    #pragma unroll
    for (int ct = 0; ct < 6; ct++) {
        #pragma unroll
        for (int ks = 0; ks < 4; ks++) {
            f16x8 bfr = *(const f16x8*)&Ws[(ct * 16 + lc) * FPAD + ks * 32 + quad * 8];
            acc[ct] = __builtin_amdgcn_mfma_f32_16x16x32_f16(afr[ks], bfr, acc[ct], 0, 0, 0);
        }
    }

    int m0 = 16 * w + quad * 4;
    #pragma unroll
    for (int r = 0; r < 4; r++) {
        int gr = row0 + m0 + r;
        if (gr < n) {
            #pragma unroll
            for (int ct = 0; ct < 6; ct++) {
                int o = ct * 16 + lc;
                h16[(size_t)gr * H + o] = (f16)fmaxf(acc[ct][r] + b[o], 0.f);
            }
        }
    }
}

// ---------------- fully fused layer (R11 + paired W staging + fused fc1) ----------------
// One block = 64 rows, 256 threads, 782 blocks (the proven R11 structure).
// Phase A: spmm gather (16 groups x 4 rows) -> hi in LDS; W experts {0,1}
// prefetched into Wl BEFORE the gather so their staging latency hides under
// it. Phase B: ctx softmax fully in registers (R11 scheme). Phase C: experts
// staged in PAIRS (36 KB Wl) -> 6 mid-loop barriers instead of 14. Last
// layer (fc1t_ != nullptr): relu(h) is written to the now-dead hi_lds,
// fc1t staged into Wl, 9 MFMAs produce out directly -- no fc1 kernel, no
// final h round-trip. LDS ~50.7 KB -> 3 blocks/CU (= grid average anyway).
// csr overread-safe (prank follows csr, all values valid node ids).

#define LF_ROWS   64
#define LF_BLOCKS ((N_NODES + LF_ROWS - 1) / LF_ROWS)   // 782
#define HPAD      104

#define ACC8(v) { _Pragma("unroll") for (int q = 0; q < 8; q++) acc[q] += (float)(v)[q]; }

__global__ __launch_bounds__(256, 4) void layer_fused(const f16* __restrict__ h16,
                                                      const int* __restrict__ rowptr,
                                                      const int* __restrict__ csr,
                                                      const float* __restrict__ cw,
                                                      const float* __restrict__ cb,
                                                      const f16* __restrict__ wfrag, // [K][9216]
                                                      f16* __restrict__ hout16,
                                                      const f16* __restrict__ fc1t_, // non-null on last layer
                                                      const float* __restrict__ fc1b,
                                                      float* __restrict__ out, int n) {
    __shared__ f16 hi_lds[LF_ROWS * HPAD];   // 13.3 KB
    __shared__ f16 Wl[2 * 9216];             // 36 KB (expert pair)
    __shared__ f16 wsh[H * K_EXP];           // 1.5 KB
    __shared__ float bs[K_EXP];
    __shared__ float fb[48];

    int tid = threadIdx.x;
    int brow = blockIdx.x * LF_ROWS;

    for (int t = tid; t < H * K_EXP; t += 256) wsh[t] = (f16)cw[t];
    if (tid < K_EXP) bs[tid] = cb[tid];
    if (fc1t_ && tid < 48) fb[tid] = (tid < C_OUT) ? fc1b[tid] : 0.f;

    // prefetch W expert pair {0,1}: staging latency hides under the gather
    for (int t = tid; t < 2304; t += 256)
        *(f16x8*)&Wl[t * 8] = *(const f16x8*)(wfrag + t * 8);

    int l = tid & 63, w = tid >> 6;
    int quad = l >> 4, li = l & 15;

    // ---- phase A: spmm for own 64 rows (group g = tid>>4 -> rows brow+g*4..+3)
    {
        int g = tid >> 4, gl = tid & 15;
        bool act = gl < 12;
        const f16* hb = h16 + gl * 8;
        for (int sub = 0; sub < 4; sub++) {
            int r = brow + g * 4 + sub;
            float acc[8] = {};
            if (r < n) {
                int j = rowptr[r], e = rowptr[r + 1];
                int4 qa = *(const int4*)(csr + j);       // overread-safe
                int4 qb = *(const int4*)(csr + j + 4);
                while (j + 8 <= e) {
                    int4 na = *(const int4*)(csr + j + 8);
                    int4 nb = *(const int4*)(csr + j + 12);
                    f16x8 v0 = {}, v1 = {}, v2 = {}, v3 = {}, v4 = {}, v5 = {}, v6 = {}, v7 = {};
                    if (act) {
                        v0 = *(const f16x8*)(hb + (size_t)qa.x * H);
                        v1 = *(const f16x8*)(hb + (size_t)qa.y * H);
                        v2 = *(const f16x8*)(hb + (size_t)qa.z * H);
                        v3 = *(const f16x8*)(hb + (size_t)qa.w * H);
                        v4 = *(const f16x8*)(hb + (size_t)qb.x * H);
                        v5 = *(const f16x8*)(hb + (size_t)qb.y * H);
                        v6 = *(const f16x8*)(hb + (size_t)qb.z * H);
                        v7 = *(const f16x8*)(hb + (size_t)qb.w * H);
                    }
                    ACC8(v0) ACC8(v1) ACC8(v2) ACC8(v3)
                    ACC8(v4) ACC8(v5) ACC8(v6) ACC8(v7)
                    j += 8; qa = na; qb = nb;
                }
                if (j + 4 <= e) {
                    f16x8 v0 = {}, v1 = {}, v2 = {}, v3 = {};
                    if (act) {
                        v0 = *(const f16x8*)(hb + (size_t)qa.x * H);
                        v1 = *(const f16x8*)(hb + (size_t)qa.y * H);
                        v2 = *(const f16x8*)(hb + (size_t)qa.z * H);
                        v3 = *(const f16x8*)(hb + (size_t)qa.w * H);
                    }
                    ACC8(v0) ACC8(v1) ACC8(v2) ACC8(v3)
                    j += 4; qa = qb;
                }
                int rem = e - j;   // 0..3
                if (rem > 0) {
                    f16x8 v0 = {}, v1 = {}, v2 = {};
                    if (act) {
                        v0 = *(const f16x8*)(hb + (size_t)qa.x * H);
                        if (rem > 1) v1 = *(const f16x8*)(hb + (size_t)qa.y * H);
                        if (rem > 2) v2 = *(const f16x8*)(hb + (size_t)qa.z * H);
                    }
                    ACC8(v0)
                    if (rem > 1) ACC8(v1)
                    if (rem > 2) ACC8(v2)
                }
            }
            if (act) {
                f16x8 o;
                #pragma unroll
                for (int q = 0; q < 8; q++) o[q] = (f16)acc[q];
                *(f16x8*)&hi_lds[(g * 4 + sub) * HPAD + gl * 8] = o;
            }
        }
    }
    __syncthreads();   // hi_lds + wsh + bs + W pair {0,1} visible

    // ---- phase B: ctx softmax in registers (all waves; lane=(node li, quarter quad))
    f16 zh[K_EXP];
    {
        float ca[K_EXP];
        #pragma unroll
        for (int k = 0; k < K_EXP; k++) ca[k] = 0.f;
        int node = brow + w * 16 + li;
        if (node < n) {
            const f16* hr = h16 + (size_t)node * H + quad * 24;
            #pragma unroll
            for (int c8 = 0; c8 < 3; c8++) {
                f16x8 v = *(const f16x8*)(hr + c8 * 8);
                #pragma unroll
                for (int jj = 0; jj < 8; jj++) {
                    float hv = (float)v[jj];
                    int d = quad * 24 + c8 * 8 + jj;
                    #pragma unroll
                    for (int k = 0; k < K_EXP; k++) ca[k] += hv * (float)wsh[d * K_EXP + k];
                }
            }
        }
        #pragma unroll
        for (int k = 0; k < K_EXP; k++) {
            ca[k] += __shfl_xor(ca[k], 16, 64);
            ca[k] += __shfl_xor(ca[k], 32, 64);
            ca[k] += bs[k];
        }
        float mx = ca[0];
        #pragma unroll
        for (int k = 1; k < K_EXP; k++) mx = fmaxf(mx, ca[k]);
        float ssum = 0.f;
        #pragma unroll
        for (int k = 0; k < K_EXP; k++) { ca[k] = __expf(ca[k] - mx); ssum += ca[k]; }
        float inv = 1.f / ssum;
        #pragma unroll
        for (int k = 0; k < K_EXP; k++) zh[k] = (f16)(ca[k] * inv);
    }

    // ---- phase C: expert GEMM (wave w -> rows brow+w*16 .. +15), paired W staging
    f16x8 afr[3];
    #pragma unroll
    for (int ks = 0; ks < 3; ks++)
        afr[ks] = *(const f16x8*)&hi_lds[(w * 16 + li) * HPAD + ks * 32 + quad * 8];

    f32x4 acc[6] = {};
    #pragma unroll
    for (int kb = 0; kb < K_EXP; kb += 2) {
        if (kb) {
            __syncthreads();           // prior pair fully consumed
            const f16* src = wfrag + (size_t)kb * 9216;
            for (int t = tid; t < 2304; t += 256)
                *(f16x8*)&Wl[t * 8] = *(const f16x8*)(src + t * 8);
            __syncthreads();
        }
        #pragma unroll
        for (int k2 = 0; k2 < 2; k2++) {
            f16 s = zh[kb + k2];
            f16x8 as0 = afr[0] * s, as1 = afr[1] * s, as2 = afr[2] * s;
            const f16* wl = &Wl[k2 * 9216];
            #pragma unroll
            for (int ct = 0; ct < 6; ct++) {
                f16x8 b0 = *(const f16x8*)&wl[ct * 1536 + 0 * 512 + l * 8];
                f16x8 b1 = *(const f16x8*)&wl[ct * 1536 + 1 * 512 + l * 8];
                f16x8 b2 = *(const f16x8*)&wl[ct * 1536 + 2 * 512 + l * 8];
                acc[ct] = __builtin_amdgcn_mfma_f32_16x16x32_f16(as0, b0, acc[ct], 0, 0, 0);
                acc[ct] = __builtin_amdgcn_mfma_f32_16x16x32_f16(as1, b1, acc[ct], 0, 0, 0);
                acc[ct] = __builtin_amdgcn_mfma_f32_16x16x32_f16(as2, b2, acc[ct], 0, 0, 0);
            }
        }
    }

    if (fc1t_) {
        // ---- fused fc1 tail: relu(h) -> hi_lds (dead after afr load), then h @ fc1t
        #pragma unroll
        for (int r = 0; r < 4; r++) {
            int lr = w * 16 + quad * 4 + r;
            int gr = brow + lr;
            #pragma unroll
            for (int ct = 0; ct < 6; ct++) {
                int o = ct * 16 + li;
                float v = 0.f;
                if (gr < n) v = fmaxf(acc[ct][r] + (float)h16[(size_t)gr * H + o], 0.f);
                hi_lds[lr * HPAD + o] = (f16)v;
            }
        }
        __syncthreads();   // h visible; all waves done reading Wl (last pair)
        for (int t = tid; t < 576; t += 256) {
            int o = t / 12, c8 = (t % 12) * 8;
            *(f16x8*)&Wl[o * HPAD + c8] = *(const f16x8*)(fc1t_ + o * H + c8);
        }
        __syncthreads();

        f16x8 a2[3];
        #pragma unroll
        for (int ks = 0; ks < 3; ks++)
            a2[ks] = *(const f16x8*)&hi_lds[(w * 16 + li) * HPAD + ks * 32 + quad * 8];

        f32x4 acc3[3] = {};
        #pragma unroll
        for (int ct = 0; ct < 3; ct++) {
            #pragma unroll
            for (int ks = 0; ks < 3; ks++) {
                f16x8 bfr = *(const f16x8*)&Wl[(ct * 16 + li) * HPAD + ks * 32 + quad * 8];
                acc3[ct] = __builtin_amdgcn_mfma_f32_16x16x32_f16(a2[ks], bfr, acc3[ct], 0, 0, 0);
            }
        }
        #pragma unroll
        for (int r = 0; r < 4; r++) {
            int gr = brow + w * 16 + quad * 4 + r;
            if (gr < n) {
                #pragma unroll
                for (int ct = 0; ct < 3; ct++) {
                    int o = ct * 16 + li;
                    if (o < C_OUT)
                        out[(size_t)gr * C_OUT + o] = acc3[ct][r] + fb[o];
                }
            }
        }
    } else {
        #pragma unroll
        for (int r = 0; r < 4; r++) {
            int gr = brow + w * 16 + quad * 4 + r;
            if (gr < n) {
                #pragma unroll
                for (int ct = 0; ct < 6; ct++) {
                    int o = ct * 16 + li;
                    float v = fmaxf(acc[ct][r] + (float)h16[(size_t)gr * H + o], 0.f);
                    hout16[(size_t)gr * H + o] = (f16)v;
                }
            }
        }
    }
}

// ---------------- launch ----------------

extern "C" void kernel_launch(void* const* d_in, const int* in_sizes, int n_in,
                              void* d_out, int out_size, void* d_ws, size_t ws_size,
                              hipStream_t stream) {
    const float* x      = (const float*)d_in[0];
    const int*   ei     = (const int*)d_in[1];
    const float* fc0_w  = (const float*)d_in[2];
    const float* fc0_b  = (const float*)d_in[3];
    const float* fc1_w  = (const float*)d_in[4];
    const float* fc1_b  = (const float*)d_in[5];
    const float* ctx_w  = (const float*)d_in[6];
    const float* ctx_b  = (const float*)d_in[7];
    const float* conv_w = (const float*)d_in[8];
    float* out = (float*)d_out;

    const size_t NH = (size_t)N_NODES * H;

    f16*   h16a = (f16*)d_ws;
    f16*   h16b = h16a + NH;
    f16*   wfrag= h16b + NH;
    f16*   fc0t = wfrag + CONV_TOT;
    f16*   fc1t = fc0t + FC0_TOT;
    int* rowptr = (int*)(fc1t + FC1_TOT);                // N+1
    int* deg    = rowptr + (N_NODES + 1);                // N
    int* csr    = deg + N_NODES;                         // E
    int* prank  = csr + N_EDGES;                         // E  (also csr overread pad)
    int* partial  = prank + N_EDGES;                     // 64

    const int* row = ei;
    const int* col = ei + N_EDGES;

    hipMemsetAsync(deg, 0, sizeof(int) * N_NODES, stream);

    count_convert<<<CNT_BLOCKS + CVT_BLOCKS, 256, 0, stream>>>(
        row, deg, prank, conv_w, fc0_w, fc1_w, wfrag, fc0t, fc1t);
    int nsb = (N_NODES + 1023) / 1024;   // 49
    scanA<<<nsb, 1024, 0, stream>>>(deg, rowptr, partial, N_NODES);
    scanC<<<nsb, 1024, 0, stream>>>(rowptr, partial, nsb, N_NODES);

    int gemm_grid = (N_NODES + 63) / 64;   // 782
    scatter_fc0<<<SCT_BLOCKS + gemm_grid, 256, 0, stream>>>(
        row, col, prank, rowptr, csr, x, fc0t, fc0_b, h16a, N_NODES);

    f16* hcur = h16a;
    f16* hnext = h16b;
    for (int i = 0; i < L_LAYERS; i++) {
        bool last = (i == L_LAYERS - 1);
        layer_fused<<<LF_BLOCKS, 256, 0, stream>>>(
            hcur, rowptr, csr,
            ctx_w + (size_t)i * H * K_EXP, ctx_b + (size_t)i * K_EXP,
            wfrag + (size_t)i * K_EXP * H * H, hnext,
            last ? fc1t : (const f16*)nullptr, fc1_b, out, N_NODES);
        f16* t = hcur; hcur = hnext; hnext = t;
    }
}

// Round 15
// 321.332 us; speedup vs baseline: 1.2342x; 1.2342x over previous
//
#include <hip/hip_runtime.h>

#define N_NODES 50000
#define N_EDGES 800000
#define DIN     128
#define H       96
#define K_EXP   8
#define L_LAYERS 4
#define C_OUT   40

typedef _Float16 f16;
typedef f16 f16x2 __attribute__((ext_vector_type(2)));
typedef f16 f16x4 __attribute__((ext_vector_type(4)));
typedef f16 f16x8 __attribute__((ext_vector_type(8)));
typedef float f32x4 __attribute__((ext_vector_type(4)));

// ---------------- CSR build + weight conversion (merged) ----------------

#define CONV_TOT (L_LAYERS * K_EXP * H * H)   // 294912
#define FC0_TOT  (DIN * H)                    // 12288
#define FC1_TOT  (48 * H)                    // 4608
#define CNT_BLOCKS ((N_EDGES + 255) / 256)            // 3125
#define CVT_BLOCKS ((CONV_TOT + FC0_TOT + FC1_TOT + 255) / 256)  // 1218

__global__ __launch_bounds__(256) void count_convert(const int* __restrict__ row,
                                                     int* __restrict__ deg,
                                                     int* __restrict__ p,
                                                     const float* __restrict__ conv_w,
                                                     const float* __restrict__ fc0_w,
                                                     const float* __restrict__ fc1_w,
                                                     f16* __restrict__ wfrag,
                                                     f16* __restrict__ fc0t,
                                                     f16* __restrict__ fc1t) {
    int tid = threadIdx.x;
    if ((int)blockIdx.x < CNT_BLOCKS) {
        int i = blockIdx.x * 256 + tid;
        if (i < N_EDGES) p[i] = atomicAdd(&deg[row[i]], 1);
    } else {
        int i = ((int)blockIdx.x - CNT_BLOCKS) * 256 + tid;
        if (i < CONV_TOT) {
            int o = i % H;
            int t = i / H;
            int d = t % H;
            int lk = t / H;
            int ct = o >> 4, lc = o & 15;
            int ks = d >> 5, quad = (d >> 3) & 3, j = d & 7;
            wfrag[(size_t)lk * 9216 + ct * 1536 + ks * 512 + (quad * 16 + lc) * 8 + j] =
                (f16)conv_w[i];
        } else if (i < CONV_TOT + FC0_TOT) {
            int j = i - CONV_TOT;      // j = d*96+o
            int o = j % H, d = j / H;
            fc0t[o * DIN + d] = (f16)fc0_w[j];
        } else if (i < CONV_TOT + FC0_TOT + FC1_TOT) {
            int j = i - CONV_TOT - FC0_TOT;  // target [o][d]
            int o = j / H, d = j % H;
            fc1t[j] = (o < C_OUT) ? (f16)fc1_w[d * C_OUT + o] : (f16)0.f;
        }
    }
}

__global__ __launch_bounds__(1024) void scanA(const int* __restrict__ deg,
                                              int* __restrict__ rowptr,
                                              int* __restrict__ partial, int n) {
    __shared__ int wsum[16];
    int tid  = threadIdx.x;
    int lane = tid & 63, wid = tid >> 6;
    int idx = blockIdx.x * 1024 + tid;
    int v = (idx < n) ? deg[idx] : 0;
    int s = v;
    #pragma unroll
    for (int off = 1; off < 64; off <<= 1) {
        int t = __shfl_up(s, off, 64);
        if (lane >= off) s += t;
    }
    if (lane == 63) wsum[wid] = s;
    __syncthreads();
    if (wid == 0 && lane < 16) {
        int w = wsum[lane];
        #pragma unroll
        for (int off = 1; off < 16; off <<= 1) {
            int t = __shfl_up(w, off, 16);
            if (lane >= off) w += t;
        }
        wsum[lane] = w;
    }
    __syncthreads();
    int waveoff = (wid == 0) ? 0 : wsum[wid - 1];
    if (idx < n) rowptr[idx + 1] = waveoff + s;
    if (tid == 1023) partial[blockIdx.x] = waveoff + s;
}

__global__ __launch_bounds__(1024) void scanC(int* __restrict__ rowptr,
                                              const int* __restrict__ partial,
                                              int nb, int n) {
    __shared__ int boff_s;
    int tid = threadIdx.x;
    if (tid < 64) {
        int v = 0;
        for (int j = tid; j < (int)blockIdx.x; j += 64) v += partial[j];
        #pragma unroll
        for (int off = 32; off >= 1; off >>= 1) v += __shfl_xor(v, off, 64);
        if (tid == 0) boff_s = v;
    }
    __syncthreads();
    int boff = boff_s;
    int idx = blockIdx.x * 1024 + tid;
    if (idx == 0) rowptr[0] = 0;
    if (idx < n) rowptr[idx + 1] += boff;
}

// ---------------- scatter (single pass) + fc0 MFMA, fused into one launch ----------------

#define SCT_BLOCKS 1024
#define FPAD 136

__global__ __launch_bounds__(256) void scatter_fc0(const int* __restrict__ row,
                                                   const int* __restrict__ col,
                                                   const int* __restrict__ p,
                                                   const int* __restrict__ rowptr,
                                                   int* __restrict__ csr,
                                                   const float* __restrict__ x,
                                                   const f16* __restrict__ fc0t,
                                                   const float* __restrict__ b,
                                                   f16* __restrict__ h16, int n) {
    __shared__ f16 As[64 * FPAD];
    __shared__ f16 Ws[96 * FPAD];
    int tid = threadIdx.x;
    if ((int)blockIdx.x < SCT_BLOCKS) {
        int stride = SCT_BLOCKS * 256;
        for (int i = blockIdx.x * 256 + tid; i < N_EDGES; i += stride)
            csr[rowptr[row[i]] + p[i]] = col[i];
        return;
    }
    int l = tid & 63, w = tid >> 6;
    int quad = l >> 4, lc = l & 15;
    int row0 = ((int)blockIdx.x - SCT_BLOCKS) * 64;

    for (int t = tid; t < 2048; t += 256) {
        int m = t >> 5, c4 = (t & 31) * 4;
        int gr = row0 + m;
        float4 v = {0.f, 0.f, 0.f, 0.f};
        if (gr < n) v = *(const float4*)(x + (size_t)gr * DIN + c4);
        f16x4 h4 = {(f16)v.x, (f16)v.y, (f16)v.z, (f16)v.w};
        *(f16x4*)&As[m * FPAD + c4] = h4;
    }
    for (int t = tid; t < 1536; t += 256) {
        int o = t >> 4, c8 = (t & 15) * 8;
        *(f16x8*)&Ws[o * FPAD + c8] = *(const f16x8*)(fc0t + o * DIN + c8);
    }
    __syncthreads();

    f16x8 afr[4];
    #pragma unroll
    for (int ks = 0; ks < 4; ks++)
        afr[ks] = *(const f16x8*)&As[(16 * w + lc) * FPAD + ks * 32 + quad * 8];

    f32x4 acc[6] = {};
    #pragma unroll
    for (int ct = 0; ct < 6; ct++) {
        #pragma unroll
        for (int ks = 0; ks < 4; ks++) {
            f16x8 bfr = *(const f16x8*)&Ws[(ct * 16 + lc) * FPAD + ks * 32 + quad * 8];
            acc[ct] = __builtin_amdgcn_mfma_f32_16x16x32_f16(afr[ks], bfr, acc[ct], 0, 0, 0);
        }
    }

    int m0 = 16 * w + quad * 4;
    #pragma unroll
    for (int r = 0; r < 4; r++) {
        int gr = row0 + m0 + r;
        if (gr < n) {
            #pragma unroll
            for (int ct = 0; ct < 6; ct++) {
                int o = ct * 16 + lc;
                h16[(size_t)gr * H + o] = (f16)fmaxf(acc[ct][r] + b[o], 0.f);
            }
        }
    }
}

// ---------------- fully fused layer (R11 exactly + fc1 tail on last layer) ----------------
// One block = 64 rows, 256 threads, 782 blocks. Phase A: spmm gather (16
// groups x 4 rows) -> hi in LDS. Phase B: ctx softmax fully in registers.
// Phase C: W staged ONE expert at a time (18 KB -- LDS stays 33.8 KB, the
// proven budget; R14 showed 51 KB loses occupancy and 30+ us). Last layer:
// relu(h) -> dead hi_lds, fc1t (4992 halfs) -> Wl, 9 MFMAs -> out. No fc1
// kernel, no final h round-trip. LDS unchanged vs R11.
// csr overread-safe (prank follows csr, all values valid node ids).

#define LF_ROWS   64
#define LF_BLOCKS ((N_NODES + LF_ROWS - 1) / LF_ROWS)   // 782
#define HPAD      104

#define ACC8(v) { _Pragma("unroll") for (int q = 0; q < 8; q++) acc[q] += (float)(v)[q]; }

__global__ __launch_bounds__(256, 4) void layer_fused(const f16* __restrict__ h16,
                                                      const int* __restrict__ rowptr,
                                                      const int* __restrict__ csr,
                                                      const float* __restrict__ cw,
                                                      const float* __restrict__ cb,
                                                      const f16* __restrict__ wfrag, // [K][9216]
                                                      f16* __restrict__ hout16,
                                                      const f16* __restrict__ fc1t_, // non-null on last layer
                                                      const float* __restrict__ fc1b,
                                                      float* __restrict__ out, int n) {
    __shared__ f16 hi_lds[LF_ROWS * HPAD];   // 13.3 KB
    __shared__ f16 Wl[9216];                 // 18 KB
    __shared__ f16 wsh[H * K_EXP];           // 1.5 KB
    __shared__ float bs[K_EXP];
    __shared__ float fb[48];

    int tid = threadIdx.x;
    int brow = blockIdx.x * LF_ROWS;

    for (int t = tid; t < H * K_EXP; t += 256) wsh[t] = (f16)cw[t];
    if (tid < K_EXP) bs[tid] = cb[tid];
    if (fc1t_ && tid < 48) fb[tid] = (tid < C_OUT) ? fc1b[tid] : 0.f;

    int l = tid & 63, w = tid >> 6;
    int quad = l >> 4, li = l & 15;

    // ---- phase A: spmm for own 64 rows (group g = tid>>4 -> rows brow+g*4..+3)
    {
        int g = tid >> 4, gl = tid & 15;
        bool act = gl < 12;
        const f16* hb = h16 + gl * 8;
        for (int sub = 0; sub < 4; sub++) {
            int r = brow + g * 4 + sub;
            float acc[8] = {};
            if (r < n) {
                int j = rowptr[r], e = rowptr[r + 1];
                int4 qa = *(const int4*)(csr + j);       // overread-safe
                int4 qb = *(const int4*)(csr + j + 4);
                while (j + 8 <= e) {
                    int4 na = *(const int4*)(csr + j + 8);
                    int4 nb = *(const int4*)(csr + j + 12);
                    f16x8 v0 = {}, v1 = {}, v2 = {}, v3 = {}, v4 = {}, v5 = {}, v6 = {}, v7 = {};
                    if (act) {
                        v0 = *(const f16x8*)(hb + (size_t)qa.x * H);
                        v1 = *(const f16x8*)(hb + (size_t)qa.y * H);
                        v2 = *(const f16x8*)(hb + (size_t)qa.z * H);
                        v3 = *(const f16x8*)(hb + (size_t)qa.w * H);
                        v4 = *(const f16x8*)(hb + (size_t)qb.x * H);
                        v5 = *(const f16x8*)(hb + (size_t)qb.y * H);
                        v6 = *(const f16x8*)(hb + (size_t)qb.z * H);
                        v7 = *(const f16x8*)(hb + (size_t)qb.w * H);
                    }
                    ACC8(v0) ACC8(v1) ACC8(v2) ACC8(v3)
                    ACC8(v4) ACC8(v5) ACC8(v6) ACC8(v7)
                    j += 8; qa = na; qb = nb;
                }
                if (j + 4 <= e) {
                    f16x8 v0 = {}, v1 = {}, v2 = {}, v3 = {};
                    if (act) {
                        v0 = *(const f16x8*)(hb + (size_t)qa.x * H);
                        v1 = *(const f16x8*)(hb + (size_t)qa.y * H);
                        v2 = *(const f16x8*)(hb + (size_t)qa.z * H);
                        v3 = *(const f16x8*)(hb + (size_t)qa.w * H);
                    }
                    ACC8(v0) ACC8(v1) ACC8(v2) ACC8(v3)
                    j += 4; qa = qb;
                }
                int rem = e - j;   // 0..3
                if (rem > 0) {
                    f16x8 v0 = {}, v1 = {}, v2 = {};
                    if (act) {
                        v0 = *(const f16x8*)(hb + (size_t)qa.x * H);
                        if (rem > 1) v1 = *(const f16x8*)(hb + (size_t)qa.y * H);
                        if (rem > 2) v2 = *(const f16x8*)(hb + (size_t)qa.z * H);
                    }
                    ACC8(v0)
                    if (rem > 1) ACC8(v1)
                    if (rem > 2) ACC8(v2)
                }
            }
            if (act) {
                f16x8 o;
                #pragma unroll
                for (int q = 0; q < 8; q++) o[q] = (f16)acc[q];
                *(f16x8*)&hi_lds[(g * 4 + sub) * HPAD + gl * 8] = o;
            }
        }
    }
    __syncthreads();   // hi_lds + wsh + bs visible to all waves

    // ---- phase B: ctx softmax in registers (all waves; lane=(node li, quarter quad))
    f16 zh[K_EXP];
    {
        float ca[K_EXP];
        #pragma unroll
        for (int k = 0; k < K_EXP; k++) ca[k] = 0.f;
        int node = brow + w * 16 + li;
        if (node < n) {
            const f16* hr = h16 + (size_t)node * H + quad * 24;
            #pragma unroll
            for (int c8 = 0; c8 < 3; c8++) {
                f16x8 v = *(const f16x8*)(hr + c8 * 8);
                #pragma unroll
                for (int jj = 0; jj < 8; jj++) {
                    float hv = (float)v[jj];
                    int d = quad * 24 + c8 * 8 + jj;
                    #pragma unroll
                    for (int k = 0; k < K_EXP; k++) ca[k] += hv * (float)wsh[d * K_EXP + k];
                }
            }
        }
        #pragma unroll
        for (int k = 0; k < K_EXP; k++) {
            ca[k] += __shfl_xor(ca[k], 16, 64);
            ca[k] += __shfl_xor(ca[k], 32, 64);
            ca[k] += bs[k];
        }
        float mx = ca[0];
        #pragma unroll
        for (int k = 1; k < K_EXP; k++) mx = fmaxf(mx, ca[k]);
        float ssum = 0.f;
        #pragma unroll
        for (int k = 0; k < K_EXP; k++) { ca[k] = __expf(ca[k] - mx); ssum += ca[k]; }
        float inv = 1.f / ssum;
        #pragma unroll
        for (int k = 0; k < K_EXP; k++) zh[k] = (f16)(ca[k] * inv);
    }

    // ---- phase C: expert GEMM (wave w -> rows brow+w*16 .. +15)
    f16x8 afr[3];
    #pragma unroll
    for (int ks = 0; ks < 3; ks++)
        afr[ks] = *(const f16x8*)&hi_lds[(w * 16 + li) * HPAD + ks * 32 + quad * 8];

    f32x4 acc[6] = {};
    #pragma unroll
    for (int k = 0; k < K_EXP; k++) {
        if (k) __syncthreads();          // prior compute done reading Wl
        const f16* src = wfrag + (size_t)k * 9216;
        for (int t = tid; t < 1152; t += 256)
            *(f16x8*)&Wl[t * 8] = *(const f16x8*)(src + t * 8);
        __syncthreads();

        f16 s = zh[k];
        f16x8 as0 = afr[0] * s, as1 = afr[1] * s, as2 = afr[2] * s;
        #pragma unroll
        for (int ct = 0; ct < 6; ct++) {
            f16x8 b0 = *(const f16x8*)&Wl[ct * 1536 + 0 * 512 + l * 8];
            f16x8 b1 = *(const f16x8*)&Wl[ct * 1536 + 1 * 512 + l * 8];
            f16x8 b2 = *(const f16x8*)&Wl[ct * 1536 + 2 * 512 + l * 8];
            acc[ct] = __builtin_amdgcn_mfma_f32_16x16x32_f16(as0, b0, acc[ct], 0, 0, 0);
            acc[ct] = __builtin_amdgcn_mfma_f32_16x16x32_f16(as1, b1, acc[ct], 0, 0, 0);
            acc[ct] = __builtin_amdgcn_mfma_f32_16x16x32_f16(as2, b2, acc[ct], 0, 0, 0);
        }
    }

    if (fc1t_) {
        // ---- fused fc1 tail: relu(h) -> hi_lds (dead after afr load), then h @ fc1t
        #pragma unroll
        for (int r = 0; r < 4; r++) {
            int lr = w * 16 + quad * 4 + r;
            int gr = brow + lr;
            #pragma unroll
            for (int ct = 0; ct < 6; ct++) {
                int o = ct * 16 + li;
                float v = 0.f;
                if (gr < n) v = fmaxf(acc[ct][r] + (float)h16[(size_t)gr * H + o], 0.f);
                hi_lds[lr * HPAD + o] = (f16)v;
            }
        }
        __syncthreads();   // h visible; all waves done reading Wl (last expert)
        for (int t = tid; t < 576; t += 256) {
            int o = t / 12, c8 = (t % 12) * 8;
            *(f16x8*)&Wl[o * HPAD + c8] = *(const f16x8*)(fc1t_ + o * H + c8);
        }
        __syncthreads();

        f16x8 a2[3];
        #pragma unroll
        for (int ks = 0; ks < 3; ks++)
            a2[ks] = *(const f16x8*)&hi_lds[(w * 16 + li) * HPAD + ks * 32 + quad * 8];

        f32x4 acc3[3] = {};
        #pragma unroll
        for (int ct = 0; ct < 3; ct++) {
            #pragma unroll
            for (int ks = 0; ks < 3; ks++) {
                f16x8 bfr = *(const f16x8*)&Wl[(ct * 16 + li) * HPAD + ks * 32 + quad * 8];
                acc3[ct] = __builtin_amdgcn_mfma_f32_16x16x32_f16(a2[ks], bfr, acc3[ct], 0, 0, 0);
            }
        }
        #pragma unroll
        for (int r = 0; r < 4; r++) {
            int gr = brow + w * 16 + quad * 4 + r;
            if (gr < n) {
                #pragma unroll
                for (int ct = 0; ct < 3; ct++) {
                    int o = ct * 16 + li;
                    if (o < C_OUT)
                        out[(size_t)gr * C_OUT + o] = acc3[ct][r] + fb[o];
                }
            }
        }
    } else {
        #pragma unroll
        for (int r = 0; r < 4; r++) {
            int gr = brow + w * 16 + quad * 4 + r;
            if (gr < n) {
                #pragma unroll
                for (int ct = 0; ct < 6; ct++) {
                    int o = ct * 16 + li;
                    float v = fmaxf(acc[ct][r] + (float)h16[(size_t)gr * H + o], 0.f);
                    hout16[(size_t)gr * H + o] = (f16)v;
                }
            }
        }
    }
}

// ---------------- launch ----------------

extern "C" void kernel_launch(void* const* d_in, const int* in_sizes, int n_in,
                              void* d_out, int out_size, void* d_ws, size_t ws_size,
                              hipStream_t stream) {
    const float* x      = (const float*)d_in[0];
    const int*   ei     = (const int*)d_in[1];
    const float* fc0_w  = (const float*)d_in[2];
    const float* fc0_b  = (const float*)d_in[3];
    const float* fc1_w  = (const float*)d_in[4];
    const float* fc1_b  = (const float*)d_in[5];
    const float* ctx_w  = (const float*)d_in[6];
    const float* ctx_b  = (const float*)d_in[7];
    const float* conv_w = (const float*)d_in[8];
    float* out = (float*)d_out;

    const size_t NH = (size_t)N_NODES * H;

    f16*   h16a = (f16*)d_ws;
    f16*   h16b = h16a + NH;
    f16*   wfrag= h16b + NH;
    f16*   fc0t = wfrag + CONV_TOT;
    f16*   fc1t = fc0t + FC0_TOT;
    int* rowptr = (int*)(fc1t + FC1_TOT);                // N+1
    int* deg    = rowptr + (N_NODES + 1);                // N
    int* csr    = deg + N_NODES;                         // E
    int* prank  = csr + N_EDGES;                         // E  (also csr overread pad)
    int* partial  = prank + N_EDGES;                     // 64

    const int* row = ei;
    const int* col = ei + N_EDGES;

    hipMemsetAsync(deg, 0, sizeof(int) * N_NODES, stream);

    count_convert<<<CNT_BLOCKS + CVT_BLOCKS, 256, 0, stream>>>(
        row, deg, prank, conv_w, fc0_w, fc1_w, wfrag, fc0t, fc1t);
    int nsb = (N_NODES + 1023) / 1024;   // 49
    scanA<<<nsb, 1024, 0, stream>>>(deg, rowptr, partial, N_NODES);
    scanC<<<nsb, 1024, 0, stream>>>(rowptr, partial, nsb, N_NODES);

    int gemm_grid = (N_NODES + 63) / 64;   // 782
    scatter_fc0<<<SCT_BLOCKS + gemm_grid, 256, 0, stream>>>(
        row, col, prank, rowptr, csr, x, fc0t, fc0_b, h16a, N_NODES);

    f16* hcur = h16a;
    f16* hnext = h16b;
    for (int i = 0; i < L_LAYERS; i++) {
        bool last = (i == L_LAYERS - 1);
        layer_fused<<<LF_BLOCKS, 256, 0, stream>>>(
            hcur, rowptr, csr,
            ctx_w + (size_t)i * H * K_EXP, ctx_b + (size_t)i * K_EXP,
            wfrag + (size_t)i * K_EXP * H * H, hnext,
            last ? fc1t : (const f16*)nullptr, fc1_b, out, N_NODES);
        f16* t = hcur; hcur = hnext; hnext = t;
    }
}